// Round 6
// baseline (13.630 us; speedup 1.0000x reference)
//
#include <hip/hip_runtime.h>

// 14-qubit statevector sim, batch 256 — fully collapsed form.
//
// Validated folds (rounds 0-1, absmax 3e-5):
//   s0 = product state (fused initial-RY + layer-0 RY/RZ/RY per qubit),
//   CNOT chain == Gray map g(l) = l ^ (l>>1), layer-1 fuses to one 2x2 per qubit.
// New collapse (this round): substituting n = g(m') in s2 = G * C * s0 gives
//   m'_q = parity(n>>q); for q<7 that is parity(n_lo>>q) XOR parity(n_hi).
// Hence the FINAL STATE IS RANK-2 SEPARABLE:
//   s2[m_hi,m_lo] = d0[m_hi] c0[m_lo] + d1[m_hi] c1[m_lo]
// with c_p = (tensor_{q<7} M_q) x_p,  x_p[u] = plo[g7(u) ^ 64p]
//      d_p = (tensor_{q>=7} M_q) y_p, y_p[u] = (u&1)==p ? phi[g7(u)] : 0
// (g7(x) = x^(x>>1) on 7 bits; g7 linear over XOR, g7(127) = 64).
// Each c/d is one wave applying 7 butterfly levels via __shfl_xor.
// Readout (second chain folded): out[l] = |s2[g(l)]|^2
//   = e0[A] f0[j] + e1[A] f1[j] + ez[A].fz[j]   (4 real FMAs)
// with A = l>>7, j = (l&127) ^ (127 * (A&1)), tables stored in readout order.

typedef float f32x2 __attribute__((ext_vector_type(2)));

constexpr int NQ    = 14;
constexpr int DIM   = 1 << NQ;     // 16384
constexpr int NT    = 256;
constexpr int SPLIT = 4;           // blocks per batch element
constexpr int CHUNK = DIM / SPLIT; // 4096 outputs per block

__device__ __forceinline__ f32x2 cmul(f32x2 a, f32x2 b) {
    return f32x2{a.x * b.x - a.y * b.y, a.x * b.y + a.y * b.x};
}
__device__ __forceinline__ int g7(int x)  { return x ^ (x >> 1); }
__device__ __forceinline__ int g7i(int x) { x ^= x >> 1; x ^= x >> 2; x ^= x >> 4; return x; }

__global__ __launch_bounds__(NT)
void qsim_kernel(const float* __restrict__ latent,
                 const float* __restrict__ weights,
                 float* __restrict__ out)
{
    __shared__ f32x2 vq [2 * NQ];      // layer-0 fused columns
    __shared__ f32x2 m1 [4 * NQ];      // layer-1 fused 2x2 matrices
    __shared__ f32x2 plo[128], phi[128];
    __shared__ f32x2 cc0[128], cc1[128], dd0[128], dd1[128];
    __shared__ float4 fj[128];         // per-j  (|c0|^2, |c1|^2, zc.x, zc.y)
    __shared__ float4 eA[128];         // per-A  (|d0|^2, |d1|^2, 2 zd.x, -2 zd.y)

    const int b   = blockIdx.x >> 2;
    const int qtr = blockIdx.x & 3;
    const int tid = threadIdx.x;

    // ---- Phase A: fused per-qubit gate parameters ----
    if (tid < NQ) {
        const int q = tid;
        const float a = weights[3 * q] + 3.14159265358979323846f * latent[b * NQ + q];
        const float t = weights[3 * q + 1];
        const float c = weights[3 * q + 2];
        const float ct = cosf(0.5f * t),       stt = sinf(0.5f * t);
        const float cp = cosf(0.5f * (a + c)), sp  = sinf(0.5f * (a + c));
        const float cm = cosf(0.5f * (a - c)), sm  = sinf(0.5f * (a - c));
        vq[2 * q + 0] = f32x2{ct * cp, -stt * cm};
        vq[2 * q + 1] = f32x2{ct * sp,  stt * sm};
    } else if (tid >= 64 && tid < 64 + NQ) {
        const int q = tid - 64;
        const float a = weights[3 * NQ + 3 * q];
        const float t = weights[3 * NQ + 3 * q + 1];
        const float c = weights[3 * NQ + 3 * q + 2];
        const float ct = cosf(0.5f * t),       stt = sinf(0.5f * t);
        const float cp = cosf(0.5f * (a + c)), sp  = sinf(0.5f * (a + c));
        const float cm = cosf(0.5f * (a - c)), sm  = sinf(0.5f * (a - c));
        m1[4 * q + 0] = f32x2{ ct * cp, -stt * cm};
        m1[4 * q + 1] = f32x2{-ct * sp,  stt * sm};
        m1[4 * q + 2] = f32x2{ ct * sp,  stt * sm};
        m1[4 * q + 3] = f32x2{ ct * cp,  stt * cm};
    }
    __syncthreads();

    // ---- Phase B: product tables (128 low / 128 high) ----
    {
        const int half = tid >> 7;       // 0: plo, 1: phi
        const int m    = tid & 127;
        const int qb   = half * 7;
        f32x2 p = {1.0f, 0.0f};
        #pragma unroll
        for (int j = 0; j < 7; ++j)
            p = cmul(p, vq[2 * (qb + j) + ((m >> j) & 1)]);
        (half ? phi : plo)[m] = p;
    }
    __syncthreads();

    // ---- Phase C: four 128-vector butterfly pipelines, one per wave ----
    {
        const int w    = tid >> 6;       // 0:c0 1:c1 2:d0 3:d1
        const int lane = tid & 63;
        const int u0 = 2 * lane, u1 = 2 * lane + 1;

        f32x2 r0, r1;
        if (w == 0)      { r0 = plo[g7(u0)];       r1 = plo[g7(u1)];       }
        else if (w == 1) { r0 = plo[g7(u0) ^ 64];  r1 = plo[g7(u1) ^ 64];  }
        else if (w == 2) { r0 = phi[g7(u0)];       r1 = f32x2{0.f, 0.f};   }
        else             { r0 = f32x2{0.f, 0.f};   r1 = phi[g7(u1)];       }

        const int mbase = (w >> 1) * 7;  // qubits 0-6 or 7-13

        // level 0: bit 0 of u lives in-register
        {
            const f32x2 M00 = m1[4 * mbase + 0], M01 = m1[4 * mbase + 1];
            const f32x2 M10 = m1[4 * mbase + 2], M11 = m1[4 * mbase + 3];
            const f32x2 n0 = cmul(M00, r0) + cmul(M01, r1);
            const f32x2 n1 = cmul(M10, r0) + cmul(M11, r1);
            r0 = n0; r1 = n1;
        }
        // levels 1..6: bit k of u == bit k-1 of lane -> shfl_xor partner
        #pragma unroll
        for (int k = 1; k < 7; ++k) {
            const int q = mbase + k;
            const f32x2 M00 = m1[4 * q + 0], M01 = m1[4 * q + 1];
            const f32x2 M10 = m1[4 * q + 2], M11 = m1[4 * q + 3];
            const int msk = 1 << (k - 1);
            const int bit = (lane >> (k - 1)) & 1;
            f32x2 p0, p1;
            p0.x = __shfl_xor(r0.x, msk, 64); p0.y = __shfl_xor(r0.y, msk, 64);
            p1.x = __shfl_xor(r1.x, msk, 64); p1.y = __shfl_xor(r1.y, msk, 64);
            const f32x2 lo0 = bit ? p0 : r0, hi0 = bit ? r0 : p0;
            const f32x2 lo1 = bit ? p1 : r1, hi1 = bit ? r1 : p1;
            const f32x2 Ma  = bit ? M10 : M00;
            const f32x2 Mb  = bit ? M11 : M01;
            r0 = cmul(Ma, lo0) + cmul(Mb, hi0);
            r1 = cmul(Ma, lo1) + cmul(Mb, hi1);
        }
        // store in readout order: cc_p[j] = c_p[g7(j)]  ->  index g7i(m)
        const int j0 = g7i(u0), j1 = g7i(u1);
        if (w == 0)      { cc0[j0] = r0; cc0[j1] = r1; }
        else if (w == 1) { cc1[j0] = r0; cc1[j1] = r1; }
        else if (w == 2) { dd0[j0] = r0; dd0[j1] = r1; }
        else             { dd1[j0] = r0; dd1[j1] = r1; }
    }
    __syncthreads();

    // ---- Phase D: pack real readout tables ----
    if (tid < 128) {
        const int j = tid;
        const f32x2 c0 = cc0[j], c1 = cc1[j];
        fj[j] = make_float4(c0.x * c0.x + c0.y * c0.y,
                            c1.x * c1.x + c1.y * c1.y,
                            c0.x * c1.x + c0.y * c1.y,     // zc.x
                            c0.y * c1.x - c0.x * c1.y);    // zc.y
    } else {
        const int A = tid - 128;
        const f32x2 d0 = dd0[A], d1 = dd1[A];
        eA[A] = make_float4(d0.x * d0.x + d0.y * d0.y,
                            d1.x * d1.x + d1.y * d1.y,
                            2.0f * (d0.x * d1.x + d0.y * d1.y),    //  2 zd.x
                           -2.0f * (d0.y * d1.x - d0.x * d1.y));   // -2 zd.y
    }
    __syncthreads();

    // ---- Phase E: readout. out[l] = e(A) . f(j), coalesced dword stores ----
    float* outb = out + (size_t)b * DIM + qtr * CHUNK;
    #pragma unroll
    for (int k = 0; k < CHUNK / NT; ++k) {
        const int ll = tid + k * NT;               // local output index
        const int l  = qtr * CHUNK + ll;           // global output index
        const int A  = l >> 7;                     // uniform per wave
        const int j  = (l & 127) ^ ((A & 1) ? 127 : 0);
        const float4 e = eA[A];
        const float4 f = fj[j];
        outb[ll] = e.x * f.x + e.y * f.y + e.z * f.z + e.w * f.w;
    }
}

extern "C" void kernel_launch(void* const* d_in, const int* in_sizes, int n_in,
                              void* d_out, int out_size, void* d_ws, size_t ws_size,
                              hipStream_t stream) {
    const float* latent  = (const float*)d_in[0];   // [256][14]
    const float* weights = (const float*)d_in[1];   // [84]
    float* out = (float*)d_out;                     // [256][16384]

    const int B = in_sizes[0] / NQ;                 // 256
    qsim_kernel<<<B * SPLIT, NT, 0, stream>>>(latent, weights, out);
}

// Round 7
// 11.561 us; speedup vs baseline: 1.1790x; 1.1790x over previous
//
#include <hip/hip_runtime.h>

// 14-qubit statevector sim, batch 256 — rank-2 separable collapsed form.
//
// Validated (rounds 0-2, absmax 3.05e-5):
//   s0 = product state (fused initial-RY + layer-0 RY/RZ/RY per qubit),
//   CNOT chain == Gray map g(l) = l ^ (l>>1), layer-1 fuses to one 2x2 per qubit,
//   final state rank-2 separable:
//     s2[m_hi,m_lo] = d0[m_hi] c0[m_lo] + d1[m_hi] c1[m_lo]
//   c_p/d_p: 128-vectors via 7 butterfly levels in one wave (__shfl_xor).
//   Readout: out[A*128+m] = e(A) . f(m ^ 127*(A&1))   (4 real FMAs)
//     f(j) = (|c0|^2, |c1|^2, Re(c0 c1*), Im-part),  e(A) = (|d0|^2, |d1|^2, 2Re, -2Im).
//
// This round: Phase E holds f in REGISTERS (SoA, 4 cols/lane), one eA broadcast
// read + one dwordx4 store per 2 rows/wave; SPLIT=2, NT=512; __sincosf prologue.

typedef float f32x2 __attribute__((ext_vector_type(2)));
typedef float f32x4 __attribute__((ext_vector_type(4)));

constexpr int NQ    = 14;
constexpr int DIM   = 1 << NQ;     // 16384
constexpr int NT    = 512;
constexpr int SPLIT = 2;           // blocks per batch element (64 rows each)

__device__ __forceinline__ f32x2 cmul(f32x2 a, f32x2 b) {
    return f32x2{a.x * b.x - a.y * b.y, a.x * b.y + a.y * b.x};
}
__device__ __forceinline__ int g7(int x)  { return x ^ (x >> 1); }
__device__ __forceinline__ int g7i(int x) { x ^= x >> 1; x ^= x >> 2; x ^= x >> 4; return x; }

__global__ __launch_bounds__(NT)
void qsim_kernel(const float* __restrict__ latent,
                 const float* __restrict__ weights,
                 float* __restrict__ out)
{
    __shared__ f32x2 vq [2 * NQ];
    __shared__ f32x2 m1 [4 * NQ];
    __shared__ f32x2 plo[128], phi[128];
    __shared__ f32x2 cc0[128], cc1[128], dd0[128], dd1[128];
    __shared__ __align__(16) float fjx[128], fjy[128], fjz[128], fjw[128];  // SoA f-table
    __shared__ f32x4 eA[128];

    const int b   = blockIdx.x >> 1;
    const int qtr = blockIdx.x & 1;        // which 64-row half of the batch row space
    const int tid = threadIdx.x;

    // ---- Phase A: fused per-qubit gate parameters ----
    if (tid < NQ) {
        const int q = tid;
        const float a = weights[3 * q] + 3.14159265358979323846f * latent[b * NQ + q];
        const float t = weights[3 * q + 1];
        const float c = weights[3 * q + 2];
        float ct, stt, cp, sp, cm, sm;
        __sincosf(0.5f * t, &stt, &ct);
        __sincosf(0.5f * (a + c), &sp, &cp);
        __sincosf(0.5f * (a - c), &sm, &cm);
        vq[2 * q + 0] = f32x2{ct * cp, -stt * cm};
        vq[2 * q + 1] = f32x2{ct * sp,  stt * sm};
    } else if (tid >= 64 && tid < 64 + NQ) {
        const int q = tid - 64;
        const float a = weights[3 * NQ + 3 * q];
        const float t = weights[3 * NQ + 3 * q + 1];
        const float c = weights[3 * NQ + 3 * q + 2];
        float ct, stt, cp, sp, cm, sm;
        __sincosf(0.5f * t, &stt, &ct);
        __sincosf(0.5f * (a + c), &sp, &cp);
        __sincosf(0.5f * (a - c), &sm, &cm);
        m1[4 * q + 0] = f32x2{ ct * cp, -stt * cm};
        m1[4 * q + 1] = f32x2{-ct * sp,  stt * sm};
        m1[4 * q + 2] = f32x2{ ct * sp,  stt * sm};
        m1[4 * q + 3] = f32x2{ ct * cp,  stt * cm};
    }
    __syncthreads();

    // ---- Phase B: product tables ----
    if (tid < 256) {
        const int half = tid >> 7;
        const int m    = tid & 127;
        const int qb   = half * 7;
        f32x2 p = {1.0f, 0.0f};
        #pragma unroll
        for (int j = 0; j < 7; ++j)
            p = cmul(p, vq[2 * (qb + j) + ((m >> j) & 1)]);
        (half ? phi : plo)[m] = p;
    }
    __syncthreads();

    // ---- Phase C: four 128-vector butterfly pipelines, one per wave ----
    if (tid < 256) {
        const int w    = tid >> 6;       // 0:c0 1:c1 2:d0 3:d1
        const int lane = tid & 63;
        const int u0 = 2 * lane, u1 = 2 * lane + 1;

        f32x2 r0, r1;
        if (w == 0)      { r0 = plo[g7(u0)];       r1 = plo[g7(u1)];       }
        else if (w == 1) { r0 = plo[g7(u0) ^ 64];  r1 = plo[g7(u1) ^ 64];  }
        else if (w == 2) { r0 = phi[g7(u0)];       r1 = f32x2{0.f, 0.f};   }
        else             { r0 = f32x2{0.f, 0.f};   r1 = phi[g7(u1)];       }

        const int mbase = (w >> 1) * 7;

        {   // level 0: bit 0 of u lives in-register
            const f32x2 M00 = m1[4 * mbase + 0], M01 = m1[4 * mbase + 1];
            const f32x2 M10 = m1[4 * mbase + 2], M11 = m1[4 * mbase + 3];
            const f32x2 n0 = cmul(M00, r0) + cmul(M01, r1);
            const f32x2 n1 = cmul(M10, r0) + cmul(M11, r1);
            r0 = n0; r1 = n1;
        }
        #pragma unroll
        for (int k = 1; k < 7; ++k) {
            const int q = mbase + k;
            const f32x2 M00 = m1[4 * q + 0], M01 = m1[4 * q + 1];
            const f32x2 M10 = m1[4 * q + 2], M11 = m1[4 * q + 3];
            const int msk = 1 << (k - 1);
            const int bit = (lane >> (k - 1)) & 1;
            f32x2 p0, p1;
            p0.x = __shfl_xor(r0.x, msk, 64); p0.y = __shfl_xor(r0.y, msk, 64);
            p1.x = __shfl_xor(r1.x, msk, 64); p1.y = __shfl_xor(r1.y, msk, 64);
            const f32x2 lo0 = bit ? p0 : r0, hi0 = bit ? r0 : p0;
            const f32x2 lo1 = bit ? p1 : r1, hi1 = bit ? r1 : p1;
            const f32x2 Ma  = bit ? M10 : M00;
            const f32x2 Mb  = bit ? M11 : M01;
            r0 = cmul(Ma, lo0) + cmul(Mb, hi0);
            r1 = cmul(Ma, lo1) + cmul(Mb, hi1);
        }
        const int j0 = g7i(u0), j1 = g7i(u1);
        if (w == 0)      { cc0[j0] = r0; cc0[j1] = r1; }
        else if (w == 1) { cc1[j0] = r0; cc1[j1] = r1; }
        else if (w == 2) { dd0[j0] = r0; dd0[j1] = r1; }
        else             { dd1[j0] = r0; dd1[j1] = r1; }
    }
    __syncthreads();

    // ---- Phase D: pack readout tables (f SoA, e AoS) ----
    if (tid < 128) {
        const int j = tid;
        const f32x2 c0 = cc0[j], c1 = cc1[j];
        fjx[j] = c0.x * c0.x + c0.y * c0.y;
        fjy[j] = c1.x * c1.x + c1.y * c1.y;
        fjz[j] = c0.x * c1.x + c0.y * c1.y;
        fjw[j] = c0.y * c1.x - c0.x * c1.y;
    } else if (tid < 256) {
        const int A = tid - 128;
        const f32x2 d0 = dd0[A], d1 = dd1[A];
        eA[A] = f32x4{d0.x * d0.x + d0.y * d0.y,
                      d1.x * d1.x + d1.y * d1.y,
                      2.0f * (d0.x * d1.x + d0.y * d1.y),
                     -2.0f * (d0.y * d1.x - d0.x * d1.y)};
    }
    __syncthreads();

    // ---- Phase E: f in registers; 1 eA read + 1 dwordx4 store per 2 rows/wave ----
    {
        const int w    = tid >> 6;          // wave 0..7
        const int lane = tid & 63;
        const int h    = lane >> 5;         // half-wave: 0 = even row, 1 = odd row
        const int s    = lane & 31;         // j-block: cols 4s..4s+3

        const f32x4 fx = *(const f32x4*)&fjx[4 * s];
        const f32x4 fy = *(const f32x4*)&fjy[4 * s];
        const f32x4 fz = *(const f32x4*)&fjz[4 * s];
        const f32x4 fw = *(const f32x4*)&fjw[4 * s];

        const int row0 = qtr * 64 + 8 * w + h;          // this half-wave's first row
        const int col  = h ? (124 - 4 * s) : (4 * s);   // odd rows: Gray flip m = j^127
        float* op = out + (size_t)b * DIM + row0 * 128 + col;

        #pragma unroll
        for (int t = 0; t < 4; ++t) {
            const f32x4 e = eA[row0 + 2 * t];           // 2-address broadcast read
            f32x4 o = e.x * fx + e.y * fy + e.z * fz + e.w * fw;
            if (h) o = f32x4{o.w, o.z, o.y, o.x};       // reversed store for flipped rows
            *(f32x4*)(op + t * 256) = o;
        }
    }
}

extern "C" void kernel_launch(void* const* d_in, const int* in_sizes, int n_in,
                              void* d_out, int out_size, void* d_ws, size_t ws_size,
                              hipStream_t stream) {
    const float* latent  = (const float*)d_in[0];   // [256][14]
    const float* weights = (const float*)d_in[1];   // [84]
    float* out = (float*)d_out;                     // [256][16384]

    const int B = in_sizes[0] / NQ;                 // 256
    qsim_kernel<<<B * SPLIT, NT, 0, stream>>>(latent, weights, out);
}